// Round 5
// baseline (230.804 us; speedup 1.0000x reference)
//
#include <hip/hip_runtime.h>

typedef unsigned short u16;
typedef unsigned int u32;
typedef __bf16 bf16x8 __attribute__((ext_vector_type(8)));
typedef float f32x4 __attribute__((ext_vector_type(4)));
typedef float f32x16 __attribute__((ext_vector_type(16)));

#define D_EMB 1024
#define T_SEQ 2048
#define NH 16
#define HD 64

#define GLB(p) ((const __attribute__((address_space(1))) unsigned int*)(p))
#define LDSP(p) ((__attribute__((address_space(3))) unsigned int*)(p))

__device__ __forceinline__ u16 f2bf(float f) {
  union { float f; unsigned u; } c; c.f = f;
  unsigned u = c.u;
  unsigned r = (u + 0x7FFFu + ((u >> 16) & 1u)) >> 16;
  return (u16)r;
}
__device__ __forceinline__ u32 fbits(float f) {
  union { float f; unsigned u; } c; c.f = f; return c.u;
}

// ---------------- fused prep: cvt x, cvt e, transpose-convert W_q/W_en/W_o ----------------
__global__ __launch_bounds__(256) void prep_kernel(
    const float* __restrict__ x, const float* __restrict__ e,
    const float* __restrict__ W_q, const float* __restrict__ W_en, const float* __restrict__ W_o,
    u16* __restrict__ xb, u16* __restrict__ eb,
    u16* __restrict__ Wqt, u16* __restrict__ Went, u16* __restrict__ Wot) {
  __shared__ float tile[32][33];
  const int bid = blockIdx.x, tid = threadIdx.x;
  if (bid < 8192) {
    const float* in = (bid < 4096) ? x : e;
    u16* out = (bid < 4096) ? xb : eb;
    int i = (bid & 4095) * 256 + tid;
    float4 v = reinterpret_cast<const float4*>(in)[i];
    ushort4 o;
    o.x = f2bf(v.x); o.y = f2bf(v.y); o.z = f2bf(v.z); o.w = f2bf(v.w);
    reinterpret_cast<ushort4*>(out)[i] = o;
    return;
  }
  const float* in; u16* out; int K, N, bx, by;
  int rem = bid - 8192;
  if (rem < 1024)      { in = W_q;  out = Wqt;  K = 1024; N = 1024; bx = rem & 31; by = rem >> 5; }
  else if (rem < 3072) { int r2 = rem - 1024; in = W_en; out = Went; K = 1024; N = 2048; bx = r2 & 63; by = r2 >> 6; }
  else                 { int r3 = rem - 3072; in = W_o;  out = Wot;  K = 1024; N = 1024; bx = r3 & 31; by = r3 >> 5; }
  int tx = tid & 31, ty = tid >> 5;
  int n0 = bx * 32, k0 = by * 32;
#pragma unroll
  for (int s = 0; s < 4; s++)
    tile[ty + 8 * s][tx] = in[(size_t)(k0 + ty + 8 * s) * N + n0 + tx];
  __syncthreads();
#pragma unroll
  for (int s = 0; s < 4; s++)
    out[(size_t)(n0 + ty + 8 * s) * K + k0 + tx] = f2bf(tile[tx][ty + 8 * s]);
}

// ---------------- fused QKV projection GEMM (dbuf global_load_lds staging) ----------------
__global__ __launch_bounds__(256) void proj_kernel(
    const u16* __restrict__ xb, const u16* __restrict__ eb,
    const u16* __restrict__ Wqt, const u16* __restrict__ Went,
    u16* __restrict__ qw, u16* __restrict__ kw, u16* __restrict__ vTw) {
  __shared__ u16 Al[2][128 * 64];
  __shared__ u16 Bl[2][128 * 64];
  const int tid = threadIdx.x;
  const int nb = blockIdx.x, mb = blockIdx.y;
  const int wave = tid >> 6, lane = tid & 63;
  const int ln15 = lane & 15, quad = lane >> 4;
  const int wm = wave & 1, wn = wave >> 1;

  const u16* A = (nb < 8) ? xb : eb;
  const u16* Wt = (nb < 8) ? (Wqt + (size_t)nb * 128 * D_EMB)
                           : (Went + ((size_t)nb * 128 - D_EMB) * D_EMB);

  const int g = (lane & 7) ^ ((lane >> 3) & 7);
  const int grow = wave * 8 + (lane >> 3);
  const u16* gA = A + (size_t)(mb * 128 + grow) * D_EMB + g * 8;
  const u16* gB = Wt + (size_t)grow * D_EMB + g * 8;

  auto stage = [&](int kb, int buf) {
    char* lA = (char*)&Al[buf][0] + wave * 1024;
    char* lB = (char*)&Bl[buf][0] + wave * 1024;
#pragma unroll
    for (int it = 0; it < 4; it++) {
      __builtin_amdgcn_global_load_lds(GLB(gA + (size_t)it * 32 * D_EMB + kb), LDSP(lA + it * 4096), 16, 0, 0);
      __builtin_amdgcn_global_load_lds(GLB(gB + (size_t)it * 32 * D_EMB + kb), LDSP(lB + it * 4096), 16, 0, 0);
    }
  };

  f32x4 acc[4][4] = {};
  stage(0, 0);

  for (int t = 0; t < 16; t++) {
    const int buf = t & 1;
    __syncthreads();                       // drains tile-t DMA; fences buf reuse
    if (t < 15) stage((t + 1) * 64, buf ^ 1);
#pragma unroll
    for (int ks = 0; ks < 2; ks++) {
      bf16x8 af[4], bfr[4];
#pragma unroll
      for (int mt = 0; mt < 4; mt++) {
        int r = wm * 64 + mt * 16 + ln15;
        af[mt] = *reinterpret_cast<const bf16x8*>(&Al[buf][r * 64 + (((ks * 4 + quad) ^ (r & 7)) * 8)]);
      }
#pragma unroll
      for (int nt = 0; nt < 4; nt++) {
        int r = wn * 64 + nt * 16 + ln15;
        bfr[nt] = *reinterpret_cast<const bf16x8*>(&Bl[buf][r * 64 + (((ks * 4 + quad) ^ (r & 7)) * 8)]);
      }
#pragma unroll
      for (int mt = 0; mt < 4; mt++)
#pragma unroll
        for (int nt = 0; nt < 4; nt++)
          acc[mt][nt] = __builtin_amdgcn_mfma_f32_16x16x32_bf16(af[mt], bfr[nt], acc[mt][nt], 0, 0, 0);
    }
  }

  const float QSCL = 0.125f * 1.44269504f;
#pragma unroll
  for (int mt = 0; mt < 4; mt++) {
#pragma unroll
    for (int nt = 0; nt < 4; nt++) {
#pragma unroll
      for (int i = 0; i < 4; i++) {
        int rr = mb * 128 + wm * 64 + mt * 16 + quad * 4 + i;
        int c  = nb * 128 + wn * 64 + nt * 16 + ln15;
        float v = acc[mt][nt][i];
        int b = rr >> 11, t = rr & 2047;
        if (c < D_EMB) {
          int h = c >> 6, d = c & 63;
          qw[(((size_t)(b * NH + h)) * T_SEQ + t) * HD + d] = f2bf(v * QSCL);
        } else if (c < 2 * D_EMB) {
          int cc = c - D_EMB; int h = cc >> 6, d = cc & 63;
          kw[(((size_t)(b * NH + h)) * T_SEQ + t) * HD + d] = f2bf(v);
        } else {
          int cc = c - 2 * D_EMB; int h = cc >> 6, d = cc & 63;
          vTw[(((size_t)(b * NH + h)) * HD + d) * T_SEQ + t] = f2bf(v);
        }
      }
    }
  }
}

// ---------------- flash attention, 32x32 MFMA, 32 q-rows/wave, dbuf DMA ----------------
__global__ __launch_bounds__(256) void attn_kernel(
    const u16* __restrict__ q, const u16* __restrict__ k,
    const u16* __restrict__ vT, u16* __restrict__ y) {
  __shared__ u16 Kl[2][64][64];
  __shared__ u16 Vl[2][64][64];
  __shared__ u16 Pl[4][32][64];

  const int bh = blockIdx.y;
  const int qt = blockIdx.x;
  const int tid = threadIdx.x;
  const int wave = tid >> 6, lane = tid & 63;
  const int q32 = lane & 31, hi = lane >> 5;
  const int b = bh >> 4, h = bh & 15;

  const int qrow = qt * 128 + wave * 32 + q32;
  const u16* qbase = q + ((size_t)bh * T_SEQ + qrow) * HD;
  bf16x8 qf[4];
#pragma unroll
  for (int s = 0; s < 4; s++)
    qf[s] = *reinterpret_cast<const bf16x8*>(qbase + s * 16 + hi * 8);

  f32x16 o2[2] = {};
  float lp = 0.f;

  const int srow = (lane >> 3) & 7;
  const int gch  = (lane & 7) ^ srow;
  const u16* kg0 = k  + ((size_t)bh * T_SEQ + wave * 16 + srow) * HD + gch * 8;
  const u16* vg0 = vT + ((size_t)bh * HD + wave * 16 + srow) * T_SEQ + gch * 8;

  auto issue_dma = [&](int t, int buf) {
    char* klb = (char*)&Kl[buf][0][0] + wave * 2048;
    char* vlb = (char*)&Vl[buf][0][0] + wave * 2048;
    const u16* kp = kg0 + (size_t)t * 64 * HD;
    const u16* vp = vg0 + t * 64;
    __builtin_amdgcn_global_load_lds(GLB(kp),             LDSP(klb),        16, 0, 0);
    __builtin_amdgcn_global_load_lds(GLB(kp + 8 * HD),    LDSP(klb + 1024), 16, 0, 0);
    __builtin_amdgcn_global_load_lds(GLB(vp),             LDSP(vlb),        16, 0, 0);
    __builtin_amdgcn_global_load_lds(GLB(vp + 8 * T_SEQ), LDSP(vlb + 1024), 16, 0, 0);
  };

  issue_dma(0, 0);

  for (int t = 0; t < 32; t++) {
    const int buf = t & 1;
    __syncthreads();
    if (t < 31) issue_dma(t + 1, buf ^ 1);

    f32x16 s2[2] = {};
#pragma unroll
    for (int s = 0; s < 4; s++)
#pragma unroll
      for (int kt2 = 0; kt2 < 2; kt2++) {
        int r = kt2 * 32 + q32;
        bf16x8 kf = *reinterpret_cast<const bf16x8*>(
            &Kl[buf][r][(((s * 2 + hi) ^ (r & 7)) * 8)]);
        s2[kt2] = __builtin_amdgcn_mfma_f32_32x32x16_bf16(kf, qf[s], s2[kt2], 0, 0, 0);
      }

#pragma unroll
    for (int kt2 = 0; kt2 < 2; kt2++)
#pragma unroll
      for (int g = 0; g < 4; g++) {
        float p0 = __builtin_amdgcn_exp2f(s2[kt2][4 * g + 0]);
        float p1 = __builtin_amdgcn_exp2f(s2[kt2][4 * g + 1]);
        float p2 = __builtin_amdgcn_exp2f(s2[kt2][4 * g + 2]);
        float p3 = __builtin_amdgcn_exp2f(s2[kt2][4 * g + 3]);
        lp += (p0 + p1) + (p2 + p3);
        u32 dw0 = __builtin_amdgcn_perm(fbits(p1), fbits(p0), 0x07060302u);
        u32 dw1 = __builtin_amdgcn_perm(fbits(p3), fbits(p2), 0x07060302u);
        int phys = (kt2 * 4 + g) ^ (q32 & 7);
        *reinterpret_cast<uint2*>(&Pl[wave][q32][phys * 8 + 4 * hi]) = make_uint2(dw0, dw1);
      }
    asm volatile("s_waitcnt lgkmcnt(0)" ::: "memory");

#pragma unroll
    for (int s = 0; s < 4; s++) {
      bf16x8 pf = *reinterpret_cast<const bf16x8*>(
          &Pl[wave][q32][(((s * 2 + hi) ^ (q32 & 7)) * 8)]);
#pragma unroll
      for (int dt = 0; dt < 2; dt++) {
        int r = dt * 32 + q32;
        bf16x8 vf = *reinterpret_cast<const bf16x8*>(
            &Vl[buf][r][(((s * 2 + hi) ^ (r & 7)) * 8)]);
        o2[dt] = __builtin_amdgcn_mfma_f32_32x32x16_bf16(vf, pf, o2[dt], 0, 0, 0);
      }
    }
  }

  lp += __shfl_xor(lp, 32, 64);
  const float inv = 1.0f / lp;

  const size_t ybase = ((size_t)b * T_SEQ + qrow) * D_EMB + h * 64;
#pragma unroll
  for (int dt = 0; dt < 2; dt++)
#pragma unroll
    for (int g = 0; g < 4; g++) {
      u16 b0 = f2bf(o2[dt][4 * g + 0] * inv), b1 = f2bf(o2[dt][4 * g + 1] * inv);
      u16 b2 = f2bf(o2[dt][4 * g + 2] * inv), b3 = f2bf(o2[dt][4 * g + 3] * inv);
      u32 dw0 = (u32)b0 | ((u32)b1 << 16);
      u32 dw1 = (u32)b2 | ((u32)b3 << 16);
      *reinterpret_cast<uint2*>(&y[ybase + dt * 32 + 8 * g + 4 * hi]) = make_uint2(dw0, dw1);
    }
}

// ---------------- output projection GEMM: 64x128 tile, dbuf staging ----------------
// grid (nb=8, mb=64); block 256. Wave (wm,wn): rows wm*32+mt*16, cols wn*64+nt*16.
__global__ __launch_bounds__(256) void oproj_kernel(
    const u16* __restrict__ yw, const u16* __restrict__ Wot, float* __restrict__ out) {
  __shared__ u16 Al[2][64 * 64];    // 8 KB per buf
  __shared__ u16 Bl[2][128 * 64];   // 16 KB per buf
  const int tid = threadIdx.x;
  const int nb = blockIdx.x, mb = blockIdx.y;
  const int wave = tid >> 6, lane = tid & 63;
  const int ln15 = lane & 15, quad = lane >> 4;
  const int wm = wave & 1, wn = wave >> 1;

  const int srow = lane >> 3;
  const int g = (lane & 7) ^ (srow & 7);
  const u16* gA = yw  + (size_t)(mb * 64 + wave * 16 + srow) * D_EMB + g * 8;
  const u16* gB = Wot + (size_t)(nb * 128 + wave * 32 + srow) * D_EMB + g * 8;

  auto stage = [&](int kb, int buf) {
    char* lA = (char*)&Al[buf][0] + wave * 2048;
    char* lB = (char*)&Bl[buf][0] + wave * 4096;
#pragma unroll
    for (int it = 0; it < 2; it++)
      __builtin_amdgcn_global_load_lds(GLB(gA + (size_t)it * 8 * D_EMB + kb), LDSP(lA + it * 1024), 16, 0, 0);
#pragma unroll
    for (int it = 0; it < 4; it++)
      __builtin_amdgcn_global_load_lds(GLB(gB + (size_t)it * 8 * D_EMB + kb), LDSP(lB + it * 1024), 16, 0, 0);
  };

  f32x4 acc[2][4] = {};
  stage(0, 0);

  for (int t = 0; t < 16; t++) {
    const int buf = t & 1;
    __syncthreads();
    if (t < 15) stage((t + 1) * 64, buf ^ 1);
#pragma unroll
    for (int ks = 0; ks < 2; ks++) {
      bf16x8 af[2], bfr[4];
#pragma unroll
      for (int mt = 0; mt < 2; mt++) {
        int r = wm * 32 + mt * 16 + ln15;
        af[mt] = *reinterpret_cast<const bf16x8*>(&Al[buf][r * 64 + (((ks * 4 + quad) ^ (r & 7)) * 8)]);
      }
#pragma unroll
      for (int nt = 0; nt < 4; nt++) {
        int r = wn * 64 + nt * 16 + ln15;
        bfr[nt] = *reinterpret_cast<const bf16x8*>(&Bl[buf][r * 64 + (((ks * 4 + quad) ^ (r & 7)) * 8)]);
      }
#pragma unroll
      for (int mt = 0; mt < 2; mt++)
#pragma unroll
        for (int nt = 0; nt < 4; nt++)
          acc[mt][nt] = __builtin_amdgcn_mfma_f32_16x16x32_bf16(af[mt], bfr[nt], acc[mt][nt], 0, 0, 0);
    }
  }

#pragma unroll
  for (int mt = 0; mt < 2; mt++)
#pragma unroll
    for (int nt = 0; nt < 4; nt++)
#pragma unroll
      for (int i = 0; i < 4; i++) {
        int rr = mb * 64 + wm * 32 + mt * 16 + quad * 4 + i;
        int c  = nb * 128 + wn * 64 + nt * 16 + ln15;
        out[(size_t)rr * D_EMB + c] = acc[mt][nt][i];
      }
}

extern "C" void kernel_launch(void* const* d_in, const int* in_sizes, int n_in,
                              void* d_out, int out_size, void* d_ws, size_t ws_size,
                              hipStream_t stream) {
  const float* x    = (const float*)d_in[0];
  const float* e    = (const float*)d_in[1];
  const float* W_en = (const float*)d_in[2];
  const float* W_q  = (const float*)d_in[3];
  const float* W_o  = (const float*)d_in[4];
  float* out = (float*)d_out;

  char* w = (char*)d_ws;
  u16* xb   = (u16*)(w);
  u16* eb   = (u16*)(w + (8u  << 20));
  u16* Wqt  = (u16*)(w + (16u << 20));
  u16* Went = (u16*)(w + (18u << 20));
  u16* Wot  = (u16*)(w + (22u << 20));
  u16* qw   = (u16*)(w + (24u << 20));
  u16* kw   = (u16*)(w + (32u << 20));
  u16* vT   = (u16*)(w + (40u << 20));
  u16* yw   = (u16*)(w + (48u << 20));

  prep_kernel<<<12288, 256, 0, stream>>>(x, e, W_q, W_en, W_o, xb, eb, Wqt, Went, Wot);
  proj_kernel<<<dim3(24, 32), 256, 0, stream>>>(xb, eb, Wqt, Went, qw, kw, vT);
  attn_kernel<<<dim3(T_SEQ / 128, 32), 256, 0, stream>>>(qw, kw, vT, yw);
  oproj_kernel<<<dim3(8, 64), 256, 0, stream>>>(yw, Wot, out);
}

// Round 7
// 205.144 us; speedup vs baseline: 1.1251x; 1.1251x over previous
//
#include <hip/hip_runtime.h>

typedef unsigned short u16;
typedef unsigned int u32;
typedef __bf16 bf16x8 __attribute__((ext_vector_type(8)));
typedef float f32x4 __attribute__((ext_vector_type(4)));
typedef float f32x16 __attribute__((ext_vector_type(16)));

#define D_EMB 1024
#define T_SEQ 2048
#define NH 16
#define HD 64

#define GLB(p) ((const __attribute__((address_space(1))) unsigned int*)(p))
#define LDSP(p) ((__attribute__((address_space(3))) unsigned int*)(p))

__device__ __forceinline__ u16 f2bf(float f) {
  union { float f; unsigned u; } c; c.f = f;
  unsigned u = c.u;
  unsigned r = (u + 0x7FFFu + ((u >> 16) & 1u)) >> 16;
  return (u16)r;
}
__device__ __forceinline__ u32 fbits(float f) {
  union { float f; unsigned u; } c; c.f = f; return c.u;
}

// ---------------- fused prep ----------------
__global__ __launch_bounds__(256) void prep_kernel(
    const float* __restrict__ x, const float* __restrict__ e,
    const float* __restrict__ W_q, const float* __restrict__ W_en, const float* __restrict__ W_o,
    u16* __restrict__ xb, u16* __restrict__ eb,
    u16* __restrict__ Wqt, u16* __restrict__ Went, u16* __restrict__ Wot) {
  __shared__ float tile[32][33];
  const int bid = blockIdx.x, tid = threadIdx.x;
  if (bid < 8192) {
    const float* in = (bid < 4096) ? x : e;
    u16* out = (bid < 4096) ? xb : eb;
    int i = (bid & 4095) * 256 + tid;
    float4 v = reinterpret_cast<const float4*>(in)[i];
    ushort4 o;
    o.x = f2bf(v.x); o.y = f2bf(v.y); o.z = f2bf(v.z); o.w = f2bf(v.w);
    reinterpret_cast<ushort4*>(out)[i] = o;
    return;
  }
  const float* in; u16* out; int K, N, bx, by;
  int rem = bid - 8192;
  if (rem < 1024)      { in = W_q;  out = Wqt;  K = 1024; N = 1024; bx = rem & 31; by = rem >> 5; }
  else if (rem < 3072) { int r2 = rem - 1024; in = W_en; out = Went; K = 1024; N = 2048; bx = r2 & 63; by = r2 >> 6; }
  else                 { int r3 = rem - 3072; in = W_o;  out = Wot;  K = 1024; N = 1024; bx = r3 & 31; by = r3 >> 5; }
  int tx = tid & 31, ty = tid >> 5;
  int n0 = bx * 32, k0 = by * 32;
#pragma unroll
  for (int s = 0; s < 4; s++)
    tile[ty + 8 * s][tx] = in[(size_t)(k0 + ty + 8 * s) * N + n0 + tx];
  __syncthreads();
#pragma unroll
  for (int s = 0; s < 4; s++)
    out[(size_t)(n0 + ty + 8 * s) * K + k0 + tx] = f2bf(tile[tx][ty + 8 * s]);
}

// ---------------- fused QKV projection GEMM (dbuf via distinct LDS arrays) ----------------
__global__ __launch_bounds__(256) void proj_kernel(
    const u16* __restrict__ xb, const u16* __restrict__ eb,
    const u16* __restrict__ Wqt, const u16* __restrict__ Went,
    u16* __restrict__ qw, u16* __restrict__ kw, u16* __restrict__ vTw) {
  __shared__ u16 Al0[128 * 64], Bl0[128 * 64];
  __shared__ u16 Al1[128 * 64], Bl1[128 * 64];
  const int tid = threadIdx.x;
  const int nb = blockIdx.x, mb = blockIdx.y;
  const int wave = tid >> 6, lane = tid & 63;
  const int ln15 = lane & 15, quad = lane >> 4;
  const int wm = wave & 1, wn = wave >> 1;

  const u16* A = (nb < 8) ? xb : eb;
  const u16* Wt = (nb < 8) ? (Wqt + (size_t)nb * 128 * D_EMB)
                           : (Went + ((size_t)nb * 128 - D_EMB) * D_EMB);

  const int g = (lane & 7) ^ ((lane >> 3) & 7);
  const int grow = wave * 8 + (lane >> 3);
  const u16* gA = A + (size_t)(mb * 128 + grow) * D_EMB + g * 8;
  const u16* gB = Wt + (size_t)grow * D_EMB + g * 8;

  auto stage = [&](int kb, u16* AL, u16* BL) {
    char* lA = (char*)AL + wave * 1024;
    char* lB = (char*)BL + wave * 1024;
#pragma unroll
    for (int it = 0; it < 4; it++) {
      __builtin_amdgcn_global_load_lds(GLB(gA + (size_t)it * 32 * D_EMB + kb), LDSP(lA + it * 4096), 16, 0, 0);
      __builtin_amdgcn_global_load_lds(GLB(gB + (size_t)it * 32 * D_EMB + kb), LDSP(lB + it * 4096), 16, 0, 0);
    }
  };

  f32x4 acc[4][4] = {};

  auto compute = [&](const u16* AL, const u16* BL) {
#pragma unroll
    for (int ks = 0; ks < 2; ks++) {
      bf16x8 af[4], bfr[4];
#pragma unroll
      for (int mt = 0; mt < 4; mt++) {
        int r = wm * 64 + mt * 16 + ln15;
        af[mt] = *reinterpret_cast<const bf16x8*>(&AL[r * 64 + (((ks * 4 + quad) ^ (r & 7)) * 8)]);
      }
#pragma unroll
      for (int nt = 0; nt < 4; nt++) {
        int r = wn * 64 + nt * 16 + ln15;
        bfr[nt] = *reinterpret_cast<const bf16x8*>(&BL[r * 64 + (((ks * 4 + quad) ^ (r & 7)) * 8)]);
      }
#pragma unroll
      for (int mt = 0; mt < 4; mt++)
#pragma unroll
        for (int nt = 0; nt < 4; nt++)
          acc[mt][nt] = __builtin_amdgcn_mfma_f32_16x16x32_bf16(af[mt], bfr[nt], acc[mt][nt], 0, 0, 0);
    }
  };

  stage(0, Al0, Bl0);
  for (int kb = 0; kb < D_EMB; kb += 128) {
    __syncthreads();
    stage(kb + 64, Al1, Bl1);          // prefetch into distinct arrays: no alias with reads below
    compute(Al0, Bl0);
    __syncthreads();
    if (kb + 128 < D_EMB) stage(kb + 128, Al0, Bl0);
    compute(Al1, Bl1);
  }

  const float QSCL = 0.125f * 1.44269504f;
#pragma unroll
  for (int mt = 0; mt < 4; mt++) {
#pragma unroll
    for (int nt = 0; nt < 4; nt++) {
#pragma unroll
      for (int i = 0; i < 4; i++) {
        int rr = mb * 128 + wm * 64 + mt * 16 + quad * 4 + i;
        int c  = nb * 128 + wn * 64 + nt * 16 + ln15;
        float v = acc[mt][nt][i];
        int b = rr >> 11, t = rr & 2047;
        if (c < D_EMB) {
          int h = c >> 6, d = c & 63;
          qw[(((size_t)(b * NH + h)) * T_SEQ + t) * HD + d] = f2bf(v * QSCL);
        } else if (c < 2 * D_EMB) {
          int cc = c - D_EMB; int h = cc >> 6, d = cc & 63;
          kw[(((size_t)(b * NH + h)) * T_SEQ + t) * HD + d] = f2bf(v);
        } else {
          int cc = c - 2 * D_EMB; int h = cc >> 6, d = cc & 63;
          vTw[(((size_t)(b * NH + h)) * HD + d) * T_SEQ + t] = f2bf(v);
        }
      }
    }
  }
}

// ---------------- flash attention, 32x32 MFMA, 32 q-rows/wave, dbuf distinct arrays ----------------
__global__ __launch_bounds__(256) void attn_kernel(
    const u16* __restrict__ q, const u16* __restrict__ k,
    const u16* __restrict__ vT, u16* __restrict__ y) {
  __shared__ u16 Kl0[64][64], Vl0[64][64];
  __shared__ u16 Kl1[64][64], Vl1[64][64];
  __shared__ u16 Pl[4][32][64];

  const int bh = blockIdx.y;
  const int qt = blockIdx.x;
  const int tid = threadIdx.x;
  const int wave = tid >> 6, lane = tid & 63;
  const int q32 = lane & 31, hi = lane >> 5;
  const int b = bh >> 4, h = bh & 15;

  const int qrow = qt * 128 + wave * 32 + q32;
  const u16* qbase = q + ((size_t)bh * T_SEQ + qrow) * HD;
  bf16x8 qf[4];
#pragma unroll
  for (int s = 0; s < 4; s++)
    qf[s] = *reinterpret_cast<const bf16x8*>(qbase + s * 16 + hi * 8);

  f32x16 o2[2] = {};
  float lp = 0.f;

  const int srow = (lane >> 3) & 7;
  const int gch  = (lane & 7) ^ srow;
  const u16* kg0 = k  + ((size_t)bh * T_SEQ + wave * 16 + srow) * HD + gch * 8;
  const u16* vg0 = vT + ((size_t)bh * HD + wave * 16 + srow) * T_SEQ + gch * 8;

  auto issue_dma = [&](int t, u16 (*KL)[64], u16 (*VL)[64]) {
    char* klb = (char*)KL + wave * 2048;
    char* vlb = (char*)VL + wave * 2048;
    const u16* kp = kg0 + (size_t)t * 64 * HD;
    const u16* vp = vg0 + t * 64;
    __builtin_amdgcn_global_load_lds(GLB(kp),             LDSP(klb),        16, 0, 0);
    __builtin_amdgcn_global_load_lds(GLB(kp + 8 * HD),    LDSP(klb + 1024), 16, 0, 0);
    __builtin_amdgcn_global_load_lds(GLB(vp),             LDSP(vlb),        16, 0, 0);
    __builtin_amdgcn_global_load_lds(GLB(vp + 8 * T_SEQ), LDSP(vlb + 1024), 16, 0, 0);
  };

  auto body = [&](const u16 (*KL)[64], const u16 (*VL)[64]) {
    f32x16 s2[2] = {};
#pragma unroll
    for (int s = 0; s < 4; s++)
#pragma unroll
      for (int kt2 = 0; kt2 < 2; kt2++) {
        int r = kt2 * 32 + q32;
        bf16x8 kf = *reinterpret_cast<const bf16x8*>(&KL[r][(((s * 2 + hi) ^ (r & 7)) * 8)]);
        s2[kt2] = __builtin_amdgcn_mfma_f32_32x32x16_bf16(kf, qf[s], s2[kt2], 0, 0, 0);
      }

#pragma unroll
    for (int kt2 = 0; kt2 < 2; kt2++)
#pragma unroll
      for (int g = 0; g < 4; g++) {
        float p0 = __builtin_amdgcn_exp2f(s2[kt2][4 * g + 0]);
        float p1 = __builtin_amdgcn_exp2f(s2[kt2][4 * g + 1]);
        float p2 = __builtin_amdgcn_exp2f(s2[kt2][4 * g + 2]);
        float p3 = __builtin_amdgcn_exp2f(s2[kt2][4 * g + 3]);
        lp += (p0 + p1) + (p2 + p3);
        u32 dw0 = __builtin_amdgcn_perm(fbits(p1), fbits(p0), 0x07060302u);
        u32 dw1 = __builtin_amdgcn_perm(fbits(p3), fbits(p2), 0x07060302u);
        int phys = (kt2 * 4 + g) ^ (q32 & 7);
        *reinterpret_cast<uint2*>(&Pl[wave][q32][phys * 8 + 4 * hi]) = make_uint2(dw0, dw1);
      }
    asm volatile("s_waitcnt lgkmcnt(0)" ::: "memory");

#pragma unroll
    for (int s = 0; s < 4; s++) {
      bf16x8 pf = *reinterpret_cast<const bf16x8*>(
          &Pl[wave][q32][(((s * 2 + hi) ^ (q32 & 7)) * 8)]);
#pragma unroll
      for (int dt = 0; dt < 2; dt++) {
        int r = dt * 32 + q32;
        bf16x8 vf = *reinterpret_cast<const bf16x8*>(&VL[r][(((s * 2 + hi) ^ (r & 7)) * 8)]);
        o2[dt] = __builtin_amdgcn_mfma_f32_32x32x16_bf16(vf, pf, o2[dt], 0, 0, 0);
      }
    }
  };

  issue_dma(0, Kl0, Vl0);
  for (int t = 0; t < 32; t += 2) {
    __syncthreads();
    issue_dma(t + 1, Kl1, Vl1);
    body(Kl0, Vl0);
    __syncthreads();
    if (t + 2 < 32) issue_dma(t + 2, Kl0, Vl0);
    body(Kl1, Vl1);
  }

  lp += __shfl_xor(lp, 32, 64);
  const float inv = 1.0f / lp;

  const size_t ybase = ((size_t)b * T_SEQ + qrow) * D_EMB + h * 64;
#pragma unroll
  for (int dt = 0; dt < 2; dt++)
#pragma unroll
    for (int g = 0; g < 4; g++) {
      u16 b0 = f2bf(o2[dt][4 * g + 0] * inv), b1 = f2bf(o2[dt][4 * g + 1] * inv);
      u16 b2 = f2bf(o2[dt][4 * g + 2] * inv), b3 = f2bf(o2[dt][4 * g + 3] * inv);
      u32 dw0 = (u32)b0 | ((u32)b1 << 16);
      u32 dw1 = (u32)b2 | ((u32)b3 << 16);
      *reinterpret_cast<uint2*>(&y[ybase + dt * 32 + 8 * g + 4 * hi]) = make_uint2(dw0, dw1);
    }
}

// ---------------- output projection: 64x128 tile, dbuf distinct arrays ----------------
__global__ __launch_bounds__(256) void oproj_kernel(
    const u16* __restrict__ yw, const u16* __restrict__ Wot, float* __restrict__ out) {
  __shared__ u16 Al0[64 * 64], Al1[64 * 64];
  __shared__ u16 Bl0[128 * 64], Bl1[128 * 64];
  const int tid = threadIdx.x;
  const int nb = blockIdx.x, mb = blockIdx.y;
  const int wave = tid >> 6, lane = tid & 63;
  const int ln15 = lane & 15, quad = lane >> 4;
  const int wm = wave & 1, wn = wave >> 1;

  const int srow = lane >> 3;
  const int g = (lane & 7) ^ (srow & 7);
  const u16* gA = yw  + (size_t)(mb * 64 + wave * 16 + srow) * D_EMB + g * 8;
  const u16* gB = Wot + (size_t)(nb * 128 + wave * 32 + srow) * D_EMB + g * 8;

  auto stage = [&](int kb, u16* AL, u16* BL) {
    char* lA = (char*)AL + wave * 2048;
    char* lB = (char*)BL + wave * 4096;
#pragma unroll
    for (int it = 0; it < 2; it++)
      __builtin_amdgcn_global_load_lds(GLB(gA + (size_t)it * 8 * D_EMB + kb), LDSP(lA + it * 1024), 16, 0, 0);
#pragma unroll
    for (int it = 0; it < 4; it++)
      __builtin_amdgcn_global_load_lds(GLB(gB + (size_t)it * 8 * D_EMB + kb), LDSP(lB + it * 1024), 16, 0, 0);
  };

  f32x4 acc[2][4] = {};

  auto compute = [&](const u16* AL, const u16* BL) {
#pragma unroll
    for (int ks = 0; ks < 2; ks++) {
      bf16x8 af[2], bfr[4];
#pragma unroll
      for (int mt = 0; mt < 2; mt++) {
        int r = wm * 32 + mt * 16 + ln15;
        af[mt] = *reinterpret_cast<const bf16x8*>(&AL[r * 64 + (((ks * 4 + quad) ^ (r & 7)) * 8)]);
      }
#pragma unroll
      for (int nt = 0; nt < 4; nt++) {
        int r = wn * 64 + nt * 16 + ln15;
        bfr[nt] = *reinterpret_cast<const bf16x8*>(&BL[r * 64 + (((ks * 4 + quad) ^ (r & 7)) * 8)]);
      }
#pragma unroll
      for (int mt = 0; mt < 2; mt++)
#pragma unroll
        for (int nt = 0; nt < 4; nt++)
          acc[mt][nt] = __builtin_amdgcn_mfma_f32_16x16x32_bf16(af[mt], bfr[nt], acc[mt][nt], 0, 0, 0);
    }
  };

  stage(0, Al0, Bl0);
  for (int kb = 0; kb < D_EMB; kb += 128) {
    __syncthreads();
    stage(kb + 64, Al1, Bl1);
    compute(Al0, Bl0);
    __syncthreads();
    if (kb + 128 < D_EMB) stage(kb + 128, Al0, Bl0);
    compute(Al1, Bl1);
  }

#pragma unroll
  for (int mt = 0; mt < 2; mt++)
#pragma unroll
    for (int nt = 0; nt < 4; nt++)
#pragma unroll
      for (int i = 0; i < 4; i++) {
        int rr = mb * 64 + wm * 32 + mt * 16 + quad * 4 + i;
        int c  = nb * 128 + wn * 64 + nt * 16 + ln15;
        out[(size_t)rr * D_EMB + c] = acc[mt][nt][i];
      }
}

extern "C" void kernel_launch(void* const* d_in, const int* in_sizes, int n_in,
                              void* d_out, int out_size, void* d_ws, size_t ws_size,
                              hipStream_t stream) {
  const float* x    = (const float*)d_in[0];
  const float* e    = (const float*)d_in[1];
  const float* W_en = (const float*)d_in[2];
  const float* W_q  = (const float*)d_in[3];
  const float* W_o  = (const float*)d_in[4];
  float* out = (float*)d_out;

  char* w = (char*)d_ws;
  u16* xb   = (u16*)(w);
  u16* eb   = (u16*)(w + (8u  << 20));
  u16* Wqt  = (u16*)(w + (16u << 20));
  u16* Went = (u16*)(w + (18u << 20));
  u16* Wot  = (u16*)(w + (22u << 20));
  u16* qw   = (u16*)(w + (24u << 20));
  u16* kw   = (u16*)(w + (32u << 20));
  u16* vT   = (u16*)(w + (40u << 20));
  u16* yw   = (u16*)(w + (48u << 20));

  prep_kernel<<<12288, 256, 0, stream>>>(x, e, W_q, W_en, W_o, xb, eb, Wqt, Went, Wot);
  proj_kernel<<<dim3(24, 32), 256, 0, stream>>>(xb, eb, Wqt, Went, qw, kw, vT);
  attn_kernel<<<dim3(T_SEQ / 128, 32), 256, 0, stream>>>(qw, kw, vT, yw);
  oproj_kernel<<<dim3(8, 64), 256, 0, stream>>>(yw, Wot, out);
}

// Round 8
// 203.256 us; speedup vs baseline: 1.1355x; 1.0093x over previous
//
#include <hip/hip_runtime.h>

typedef unsigned short u16;
typedef unsigned int u32;
typedef __bf16 bf16x8 __attribute__((ext_vector_type(8)));
typedef float f32x4 __attribute__((ext_vector_type(4)));
typedef float f32x16 __attribute__((ext_vector_type(16)));

#define D_EMB 1024
#define T_SEQ 2048
#define NH 16
#define HD 64

#define GLB(p) ((const __attribute__((address_space(1))) unsigned int*)(p))
#define LDSP(p) ((__attribute__((address_space(3))) unsigned int*)(p))

__device__ __forceinline__ u16 f2bf(float f) {
  union { float f; unsigned u; } c; c.f = f;
  unsigned u = c.u;
  unsigned r = (u + 0x7FFFu + ((u >> 16) & 1u)) >> 16;
  return (u16)r;
}
__device__ __forceinline__ u32 fbits(float f) {
  union { float f; unsigned u; } c; c.f = f; return c.u;
}

// ---------------- fused prep ----------------
__global__ __launch_bounds__(256) void prep_kernel(
    const float* __restrict__ x, const float* __restrict__ e,
    const float* __restrict__ W_q, const float* __restrict__ W_en, const float* __restrict__ W_o,
    u16* __restrict__ xb, u16* __restrict__ eb,
    u16* __restrict__ Wqt, u16* __restrict__ Went, u16* __restrict__ Wot) {
  __shared__ float tile[32][33];
  const int bid = blockIdx.x, tid = threadIdx.x;
  if (bid < 8192) {
    const float* in = (bid < 4096) ? x : e;
    u16* out = (bid < 4096) ? xb : eb;
    int i = (bid & 4095) * 256 + tid;
    float4 v = reinterpret_cast<const float4*>(in)[i];
    ushort4 o;
    o.x = f2bf(v.x); o.y = f2bf(v.y); o.z = f2bf(v.z); o.w = f2bf(v.w);
    reinterpret_cast<ushort4*>(out)[i] = o;
    return;
  }
  const float* in; u16* out; int K, N, bx, by;
  int rem = bid - 8192;
  if (rem < 1024)      { in = W_q;  out = Wqt;  K = 1024; N = 1024; bx = rem & 31; by = rem >> 5; }
  else if (rem < 3072) { int r2 = rem - 1024; in = W_en; out = Went; K = 1024; N = 2048; bx = r2 & 63; by = r2 >> 6; }
  else                 { int r3 = rem - 3072; in = W_o;  out = Wot;  K = 1024; N = 1024; bx = r3 & 31; by = r3 >> 5; }
  int tx = tid & 31, ty = tid >> 5;
  int n0 = bx * 32, k0 = by * 32;
#pragma unroll
  for (int s = 0; s < 4; s++)
    tile[ty + 8 * s][tx] = in[(size_t)(k0 + ty + 8 * s) * N + n0 + tx];
  __syncthreads();
#pragma unroll
  for (int s = 0; s < 4; s++)
    out[(size_t)(n0 + ty + 8 * s) * K + k0 + tx] = f2bf(tile[tx][ty + 8 * s]);
}

// ---------------- fused QKV projection GEMM: 128x128, BK=32, dbuf distinct arrays ----------------
// LDS 32 KB -> 4 blocks/CU. Swizzle: phys chunk = logical ^ ((row>>1)&3); 16B chunks, 64B rows.
__global__ __launch_bounds__(256) void proj_kernel(
    const u16* __restrict__ xb, const u16* __restrict__ eb,
    const u16* __restrict__ Wqt, const u16* __restrict__ Went,
    u16* __restrict__ qw, u16* __restrict__ kw, u16* __restrict__ vTw) {
  __shared__ u16 Al0[128 * 32], Bl0[128 * 32];
  __shared__ u16 Al1[128 * 32], Bl1[128 * 32];
  const int tid = threadIdx.x;
  const int nb = blockIdx.x, mb = blockIdx.y;
  const int wave = tid >> 6, lane = tid & 63;
  const int ln15 = lane & 15, quad = lane >> 4;
  const int wm = wave & 1, wn = wave >> 1;

  const u16* A = (nb < 8) ? xb : eb;
  const u16* Wt = (nb < 8) ? (Wqt + (size_t)nb * 128 * D_EMB)
                           : (Went + ((size_t)nb * 128 - D_EMB) * D_EMB);

  const int srow = lane >> 2, sch = lane & 3;
  const int gch = sch ^ ((srow >> 1) & 3);
  const u16* gA = A + (size_t)(mb * 128 + wave * 32 + srow) * D_EMB + gch * 8;
  const u16* gB = Wt + (size_t)(wave * 32 + srow) * D_EMB + gch * 8;

  auto stage = [&](int kb, u16* AL, u16* BL) {
    char* lA = (char*)AL + wave * 2048;
    char* lB = (char*)BL + wave * 2048;
#pragma unroll
    for (int it = 0; it < 2; it++) {
      __builtin_amdgcn_global_load_lds(GLB(gA + (size_t)it * 16 * D_EMB + kb), LDSP(lA + it * 1024), 16, 0, 0);
      __builtin_amdgcn_global_load_lds(GLB(gB + (size_t)it * 16 * D_EMB + kb), LDSP(lB + it * 1024), 16, 0, 0);
    }
  };

  f32x4 acc[4][4] = {};

  auto compute = [&](const u16* AL, const u16* BL) {
    bf16x8 af[4], bfr[4];
#pragma unroll
    for (int mt = 0; mt < 4; mt++) {
      int r = wm * 64 + mt * 16 + ln15;
      af[mt] = *reinterpret_cast<const bf16x8*>(&AL[r * 32 + ((quad ^ ((r >> 1) & 3)) * 8)]);
    }
#pragma unroll
    for (int nt = 0; nt < 4; nt++) {
      int r = wn * 64 + nt * 16 + ln15;
      bfr[nt] = *reinterpret_cast<const bf16x8*>(&BL[r * 32 + ((quad ^ ((r >> 1) & 3)) * 8)]);
    }
#pragma unroll
    for (int mt = 0; mt < 4; mt++)
#pragma unroll
      for (int nt = 0; nt < 4; nt++)
        acc[mt][nt] = __builtin_amdgcn_mfma_f32_16x16x32_bf16(af[mt], bfr[nt], acc[mt][nt], 0, 0, 0);
  };

  stage(0, Al0, Bl0);
  for (int kb = 0; kb < D_EMB; kb += 64) {
    __syncthreads();
    stage(kb + 32, Al1, Bl1);
    compute(Al0, Bl0);
    __syncthreads();
    if (kb + 64 < D_EMB) stage(kb + 64, Al0, Bl0);
    compute(Al1, Bl1);
  }

  const float QSCL = 0.125f * 1.44269504f;
#pragma unroll
  for (int mt = 0; mt < 4; mt++) {
#pragma unroll
    for (int nt = 0; nt < 4; nt++) {
#pragma unroll
      for (int i = 0; i < 4; i++) {
        int rr = mb * 128 + wm * 64 + mt * 16 + quad * 4 + i;
        int c  = nb * 128 + wn * 64 + nt * 16 + ln15;
        float v = acc[mt][nt][i];
        int b = rr >> 11, t = rr & 2047;
        if (c < D_EMB) {
          int h = c >> 6, d = c & 63;
          qw[(((size_t)(b * NH + h)) * T_SEQ + t) * HD + d] = f2bf(v * QSCL);
        } else if (c < 2 * D_EMB) {
          int cc = c - D_EMB; int h = cc >> 6, d = cc & 63;
          kw[(((size_t)(b * NH + h)) * T_SEQ + t) * HD + d] = f2bf(v);
        } else {
          int cc = c - 2 * D_EMB; int h = cc >> 6, d = cc & 63;
          vTw[(((size_t)(b * NH + h)) * HD + d) * T_SEQ + t] = f2bf(v);
        }
      }
    }
  }
}

// ---------------- flash attention (unchanged from R7) ----------------
__global__ __launch_bounds__(256) void attn_kernel(
    const u16* __restrict__ q, const u16* __restrict__ k,
    const u16* __restrict__ vT, u16* __restrict__ y) {
  __shared__ u16 Kl0[64][64], Vl0[64][64];
  __shared__ u16 Kl1[64][64], Vl1[64][64];
  __shared__ u16 Pl[4][32][64];

  const int bh = blockIdx.y;
  const int qt = blockIdx.x;
  const int tid = threadIdx.x;
  const int wave = tid >> 6, lane = tid & 63;
  const int q32 = lane & 31, hi = lane >> 5;
  const int b = bh >> 4, h = bh & 15;

  const int qrow = qt * 128 + wave * 32 + q32;
  const u16* qbase = q + ((size_t)bh * T_SEQ + qrow) * HD;
  bf16x8 qf[4];
#pragma unroll
  for (int s = 0; s < 4; s++)
    qf[s] = *reinterpret_cast<const bf16x8*>(qbase + s * 16 + hi * 8);

  f32x16 o2[2] = {};
  float lp = 0.f;

  const int srow = (lane >> 3) & 7;
  const int gch  = (lane & 7) ^ srow;
  const u16* kg0 = k  + ((size_t)bh * T_SEQ + wave * 16 + srow) * HD + gch * 8;
  const u16* vg0 = vT + ((size_t)bh * HD + wave * 16 + srow) * T_SEQ + gch * 8;

  auto issue_dma = [&](int t, u16 (*KL)[64], u16 (*VL)[64]) {
    char* klb = (char*)KL + wave * 2048;
    char* vlb = (char*)VL + wave * 2048;
    const u16* kp = kg0 + (size_t)t * 64 * HD;
    const u16* vp = vg0 + t * 64;
    __builtin_amdgcn_global_load_lds(GLB(kp),             LDSP(klb),        16, 0, 0);
    __builtin_amdgcn_global_load_lds(GLB(kp + 8 * HD),    LDSP(klb + 1024), 16, 0, 0);
    __builtin_amdgcn_global_load_lds(GLB(vp),             LDSP(vlb),        16, 0, 0);
    __builtin_amdgcn_global_load_lds(GLB(vp + 8 * T_SEQ), LDSP(vlb + 1024), 16, 0, 0);
  };

  auto body = [&](const u16 (*KL)[64], const u16 (*VL)[64]) {
    f32x16 s2[2] = {};
#pragma unroll
    for (int s = 0; s < 4; s++)
#pragma unroll
      for (int kt2 = 0; kt2 < 2; kt2++) {
        int r = kt2 * 32 + q32;
        bf16x8 kf = *reinterpret_cast<const bf16x8*>(&KL[r][(((s * 2 + hi) ^ (r & 7)) * 8)]);
        s2[kt2] = __builtin_amdgcn_mfma_f32_32x32x16_bf16(kf, qf[s], s2[kt2], 0, 0, 0);
      }

#pragma unroll
    for (int kt2 = 0; kt2 < 2; kt2++)
#pragma unroll
      for (int g = 0; g < 4; g++) {
        float p0 = __builtin_amdgcn_exp2f(s2[kt2][4 * g + 0]);
        float p1 = __builtin_amdgcn_exp2f(s2[kt2][4 * g + 1]);
        float p2 = __builtin_amdgcn_exp2f(s2[kt2][4 * g + 2]);
        float p3 = __builtin_amdgcn_exp2f(s2[kt2][4 * g + 3]);
        lp += (p0 + p1) + (p2 + p3);
        u32 dw0 = __builtin_amdgcn_perm(fbits(p1), fbits(p0), 0x07060302u);
        u32 dw1 = __builtin_amdgcn_perm(fbits(p3), fbits(p2), 0x07060302u);
        int phys = (kt2 * 4 + g) ^ (q32 & 7);
        *reinterpret_cast<uint2*>(&Pl[wave][q32][phys * 8 + 4 * hi]) = make_uint2(dw0, dw1);
      }
    asm volatile("s_waitcnt lgkmcnt(0)" ::: "memory");

#pragma unroll
    for (int s = 0; s < 4; s++) {
      bf16x8 pf = *reinterpret_cast<const bf16x8*>(
          &Pl[wave][q32][(((s * 2 + hi) ^ (q32 & 7)) * 8)]);
#pragma unroll
      for (int dt = 0; dt < 2; dt++) {
        int r = dt * 32 + q32;
        bf16x8 vf = *reinterpret_cast<const bf16x8*>(&VL[r][(((s * 2 + hi) ^ (r & 7)) * 8)]);
        o2[dt] = __builtin_amdgcn_mfma_f32_32x32x16_bf16(vf, pf, o2[dt], 0, 0, 0);
      }
    }
  };

  issue_dma(0, Kl0, Vl0);
  for (int t = 0; t < 32; t += 2) {
    __syncthreads();
    issue_dma(t + 1, Kl1, Vl1);
    body(Kl0, Vl0);
    __syncthreads();
    if (t + 2 < 32) issue_dma(t + 2, Kl0, Vl0);
    body(Kl1, Vl1);
  }

  lp += __shfl_xor(lp, 32, 64);
  const float inv = 1.0f / lp;

  const size_t ybase = ((size_t)b * T_SEQ + qrow) * D_EMB + h * 64;
#pragma unroll
  for (int dt = 0; dt < 2; dt++)
#pragma unroll
    for (int g = 0; g < 4; g++) {
      u16 b0 = f2bf(o2[dt][4 * g + 0] * inv), b1 = f2bf(o2[dt][4 * g + 1] * inv);
      u16 b2 = f2bf(o2[dt][4 * g + 2] * inv), b3 = f2bf(o2[dt][4 * g + 3] * inv);
      u32 dw0 = (u32)b0 | ((u32)b1 << 16);
      u32 dw1 = (u32)b2 | ((u32)b3 << 16);
      *reinterpret_cast<uint2*>(&y[ybase + dt * 32 + 8 * g + 4 * hi]) = make_uint2(dw0, dw1);
    }
}

// ---------------- output projection: 64x128 tile, BK=32, dbuf distinct arrays ----------------
// LDS 24 KB. A: 64x32 (wave stages 16 rows, 1 instr); B: 128x32 (wave 32 rows, 2 instrs).
__global__ __launch_bounds__(256) void oproj_kernel(
    const u16* __restrict__ yw, const u16* __restrict__ Wot, float* __restrict__ out) {
  __shared__ u16 Al0[64 * 32], Al1[64 * 32];
  __shared__ u16 Bl0[128 * 32], Bl1[128 * 32];
  const int tid = threadIdx.x;
  const int nb = blockIdx.x, mb = blockIdx.y;
  const int wave = tid >> 6, lane = tid & 63;
  const int ln15 = lane & 15, quad = lane >> 4;
  const int wm = wave & 1, wn = wave >> 1;

  const int srow = lane >> 2, sch = lane & 3;
  const int gch = sch ^ ((srow >> 1) & 3);
  const u16* gA = yw  + (size_t)(mb * 64 + wave * 16 + srow) * D_EMB + gch * 8;
  const u16* gB = Wot + (size_t)(nb * 128 + wave * 32 + srow) * D_EMB + gch * 8;

  auto stage = [&](int kb, u16* AL, u16* BL) {
    char* lA = (char*)AL + wave * 1024;
    char* lB = (char*)BL + wave * 2048;
    __builtin_amdgcn_global_load_lds(GLB(gA + kb), LDSP(lA), 16, 0, 0);
#pragma unroll
    for (int it = 0; it < 2; it++)
      __builtin_amdgcn_global_load_lds(GLB(gB + (size_t)it * 16 * D_EMB + kb), LDSP(lB + it * 1024), 16, 0, 0);
  };

  f32x4 acc[2][4] = {};

  auto compute = [&](const u16* AL, const u16* BL) {
    bf16x8 af[2], bfr[4];
#pragma unroll
    for (int mt = 0; mt < 2; mt++) {
      int r = wm * 32 + mt * 16 + ln15;
      af[mt] = *reinterpret_cast<const bf16x8*>(&AL[r * 32 + ((quad ^ ((r >> 1) & 3)) * 8)]);
    }
#pragma unroll
    for (int nt = 0; nt < 4; nt++) {
      int r = wn * 64 + nt * 16 + ln15;
      bfr[nt] = *reinterpret_cast<const bf16x8*>(&BL[r * 32 + ((quad ^ ((r >> 1) & 3)) * 8)]);
    }
#pragma unroll
    for (int mt = 0; mt < 2; mt++)
#pragma unroll
      for (int nt = 0; nt < 4; nt++)
        acc[mt][nt] = __builtin_amdgcn_mfma_f32_16x16x32_bf16(af[mt], bfr[nt], acc[mt][nt], 0, 0, 0);
  };

  stage(0, Al0, Bl0);
  for (int kb = 0; kb < D_EMB; kb += 64) {
    __syncthreads();
    stage(kb + 32, Al1, Bl1);
    compute(Al0, Bl0);
    __syncthreads();
    if (kb + 64 < D_EMB) stage(kb + 64, Al0, Bl0);
    compute(Al1, Bl1);
  }

#pragma unroll
  for (int mt = 0; mt < 2; mt++)
#pragma unroll
    for (int nt = 0; nt < 4; nt++)
#pragma unroll
      for (int i = 0; i < 4; i++) {
        int rr = mb * 64 + wm * 32 + mt * 16 + quad * 4 + i;
        int c  = nb * 128 + wn * 64 + nt * 16 + ln15;
        out[(size_t)rr * D_EMB + c] = acc[mt][nt][i];
      }
}

extern "C" void kernel_launch(void* const* d_in, const int* in_sizes, int n_in,
                              void* d_out, int out_size, void* d_ws, size_t ws_size,
                              hipStream_t stream) {
  const float* x    = (const float*)d_in[0];
  const float* e    = (const float*)d_in[1];
  const float* W_en = (const float*)d_in[2];
  const float* W_q  = (const float*)d_in[3];
  const float* W_o  = (const float*)d_in[4];
  float* out = (float*)d_out;

  char* w = (char*)d_ws;
  u16* xb   = (u16*)(w);
  u16* eb   = (u16*)(w + (8u  << 20));
  u16* Wqt  = (u16*)(w + (16u << 20));
  u16* Went = (u16*)(w + (18u << 20));
  u16* Wot  = (u16*)(w + (22u << 20));
  u16* qw   = (u16*)(w + (24u << 20));
  u16* kw   = (u16*)(w + (32u << 20));
  u16* vT   = (u16*)(w + (40u << 20));
  u16* yw   = (u16*)(w + (48u << 20));

  prep_kernel<<<12288, 256, 0, stream>>>(x, e, W_q, W_en, W_o, xb, eb, Wqt, Went, Wot);
  proj_kernel<<<dim3(24, 32), 256, 0, stream>>>(xb, eb, Wqt, Went, qw, kw, vT);
  attn_kernel<<<dim3(T_SEQ / 128, 32), 256, 0, stream>>>(qw, kw, vT, yw);
  oproj_kernel<<<dim3(8, 64), 256, 0, stream>>>(yw, Wot, out);
}